// Round 10
// baseline (118.438 us; speedup 1.0000x reference)
//
#include <hip/hip_runtime.h>
#include <hip/hip_bf16.h>

typedef unsigned short ushortT;
typedef __attribute__((ext_vector_type(8))) short bf16x8;
typedef __attribute__((ext_vector_type(4))) float f32x4;

#define N_NODES 384
#define KNBR 60
#define SUBK 20
#define NEDGE (N_NODES * KNBR)
#define EPSC 1e-8f
#define INV_SQRT_CZ 0.08838834764831845f   // 1/sqrt(128)
#define MU_STEP (20.0f / 63.0f)            // linspace(0,20,64) step
#define INV_MU_STEP (63.0f / 20.0f)
#define INV_SIGMA 3.2f                     // 1/(20/64)

__device__ __forceinline__ float bflo(unsigned int u) { return __uint_as_float(u << 16); }
__device__ __forceinline__ float bfhi(unsigned int u) { return __uint_as_float(u & 0xffff0000u); }
__device__ __forceinline__ ushortT f2bu(float v) {  // f32 -> bf16 bits, RNE
  union { float f; unsigned int u; } c;
  c.f = v;
  return (ushortT)((c.u + 0x7fffu + ((c.u >> 16) & 1u)) >> 16);
}
__device__ __forceinline__ unsigned int pack2bf(float x, float y) {
  return (unsigned int)f2bu(x) | ((unsigned int)f2bu(y) << 16);
}
__device__ __forceinline__ ushortT f2h(float x) {
  _Float16 h = (_Float16)x;
  return __builtin_bit_cast(ushortT, h);
}
__device__ __forceinline__ float h2f(ushortT u) {
  return (float)__builtin_bit_cast(_Float16, u);
}

// Fused prep: blocks 0..95 = gate projection (4 nodes/block, 64 lanes each);
// blocks 96..351 = weight packing into MFMA fragment order + bias concat.
__global__ __launch_bounds__(256) void prep_kernel(
    const float* __restrict__ nf, const float* __restrict__ Wg, float* __restrict__ g,
    const float* __restrict__ Wqk, const float* __restrict__ bqk,
    const float* __restrict__ Wv, const float* __restrict__ bv,
    const float* __restrict__ Wout,
    ushortT* __restrict__ Wp1, ushortT* __restrict__ Wp2, float* __restrict__ bc) {
  int b = blockIdx.x, tid = threadIdx.x;
  if (b < 96) {
    int n = b * 4 + (tid >> 6), t = tid & 63;
    float a = nf[n * 128 + t];
    float bb = nf[n * 128 + 64 + t];
    float acc[8];
#pragma unroll
    for (int h = 0; h < 4; ++h) {
      acc[h]     = a * Wg[t * 4 + h]         + bb * Wg[(t + 64) * 4 + h];
      acc[4 + h] = a * Wg[(128 + t) * 4 + h] + bb * Wg[(192 + t) * 4 + h];
    }
#pragma unroll
    for (int i = 0; i < 8; ++i)
#pragma unroll
      for (int off = 32; off >= 1; off >>= 1) acc[i] += __shfl_xor(acc[i], off, 64);
    if (t == 0) {
#pragma unroll
      for (int i = 0; i < 8; ++i) g[n * 8 + i] = acc[i];
    }
  } else {
    int i = (b - 96) * 256 + tid;  // 65536 total
    if (i < 49152) {
      int j = i & 7, l = (i >> 3) & 63, t = (i >> 9) & 3;
      int nt = (i >> 11) % 12, ny = (i >> 11) / 12;
      int nn = ny * 192 + nt * 16 + (l & 15);
      int k = t * 32 + (l >> 4) * 8 + j;
      float v = (nn < 256) ? Wqk[k * 256 + nn] : Wv[k * 128 + (nn - 256)];
      Wp1[i] = f2bu(v);
    } else {
      int i2 = i - 49152;  // 16384
      int j = i2 & 7, l = (i2 >> 3) & 63, t = (i2 >> 9) & 3, nt = (i2 >> 11);
      int nn = nt * 16 + (l & 15);
      int k = t * 32 + (l >> 4) * 8 + j;
      Wp2[i2] = f2bu(Wout[k * 128 + nn]);
    }
    if (i < 384) bc[i] = (i < 256) ? bqk[i] : bv[i - 256];
  }
}

// One block per node, 512 threads (8 waves, two 4-wave groups). Same structure as
// round 8 (weights direct from global, read once per block -> L2-resident), but
// kvb uses a c-major conflict-free layout: dim d = hd*16 + c*8 + e stored at byte
// c*128 + hd*16 + 2e (XOR (row&7)<<4). Phase-3: one b128 per (c) covers a
// contiguous 128B half per row -> all 32 banks exactly once -> conflict-free.
__global__ __launch_bounds__(512, 4) void fused_kernel(
    const float* __restrict__ ef, const ushortT* __restrict__ Wp1,
    const ushortT* __restrict__ Wp2, const float* __restrict__ bc,
    const float* __restrict__ bout, const float* __restrict__ g,
    const float* __restrict__ node_trans, const int* __restrict__ edge_index,
    const int* __restrict__ sub_idx, const float* __restrict__ W_db,
    const float* __restrict__ b_db, const float* __restrict__ b_gate,
    float* __restrict__ outp) {
  __shared__ __align__(16) ushortT kvb[KNBR * 256];     // 30720 B
  __shared__ __align__(16) ushortT updq[64 * 136];      // 17408 B (q then upd, pad 8/row)
  __shared__ __align__(16) ushortT biasb[KNBR * SUBK * 4];  // 9600 B, f16
  __shared__ ushortT sub_lds[KNBR * SUBK];              // 2400 B
  __shared__ float trs[KNBR * 3];                       // 720 B
  __shared__ float gg[KNBR * 8];                        // 1920 B

  int n = blockIdx.x, tid = threadIdx.x;
  int e0 = n * KNBR;
  int w = tid >> 6, l = tid & 63;
  int lr = l & 15, lc = l >> 4;
  int rowA = (w & 3) * 16 + lr;          // 0..63 (rows 60..63 pad)
  int rowAc = min(rowA, KNBR - 1);

  // ---- phase 0: stage trs/gg + load A fragments ----
  if (tid < KNBR) {
    int dst = edge_index[e0 + tid];
#pragma unroll
    for (int c = 0; c < 3; ++c) trs[tid * 3 + c] = node_trans[dst * 3 + c];
#pragma unroll
    for (int i = 0; i < 8; ++i) gg[tid * 8 + i] = g[dst * 8 + i];
  }
  bf16x8 afrag[4];
#pragma unroll
  for (int t = 0; t < 4; ++t) {
    const float* ap = ef + (size_t)(e0 + rowAc) * 128 + t * 32 + lc * 8;
    float4 lo = *(const float4*)ap;
    float4 hi = *(const float4*)(ap + 4);
    bf16x8 a;
    a[0] = (short)f2bu(lo.x); a[1] = (short)f2bu(lo.y);
    a[2] = (short)f2bu(lo.z); a[3] = (short)f2bu(lo.w);
    a[4] = (short)f2bu(hi.x); a[5] = (short)f2bu(hi.y);
    a[6] = (short)f2bu(hi.z); a[7] = (short)f2bu(hi.w);
    afrag[t] = a;
  }

  // ---- phase 1: qkv projection, 12 col-tiles per group, no barriers ----
  int Tbase = (tid >> 8) * 12;
#pragma unroll
  for (int Ti = 0; Ti < 12; ++Ti) {
    int T = Tbase + Ti;
    f32x4 acc = {0.f, 0.f, 0.f, 0.f};
#pragma unroll
    for (int t = 0; t < 4; ++t) {
      bf16x8 bfrag = *(const bf16x8*)(Wp1 + ((T * 4 + t) * 64 + l) * 8);
      acc = __builtin_amdgcn_mfma_f32_16x16x32_bf16(bfrag, afrag[t], acc, 0, 0, 0);
    }
    int col0 = T * 16 + lc * 4;
    float4 bi = *(const float4*)(bc + col0);
    float o0 = acc[0] + bi.x, o1 = acc[1] + bi.y;
    float o2 = acc[2] + bi.z, o3 = acc[3] + bi.w;
    if (T < 8) {  // q: scale, straight to updq (bf16)
      uint2 o;
      o.x = pack2bf(o0 * INV_SQRT_CZ, o1 * INV_SQRT_CZ);
      o.y = pack2bf(o2 * INV_SQRT_CZ, o3 * INV_SQRT_CZ);
      *(uint2*)(updq + rowA * 136 + col0) = o;
    } else if (rowA < KNBR) {  // k,v -> kvb (c-major, swizzled)
      uint2 o;
      o.x = pack2bf(o0, o1);
      o.y = pack2bf(o2, o3);
      int colk = col0 - 128;                  // 0..255
      int base_b = (colk & 128) << 1;         // 0 (K) or 256 (V)
      int d = colk & 127;
      int inner = (((d >> 3) & 1) * 128 + (d >> 4) * 16 + (d & 7) * 2) ^ ((rowA & 7) << 4);
      *(uint2*)((char*)kvb + rowA * 512 + base_b + inner) = o;
    }
  }
  __syncthreads();  // A: trs/gg visible for phase 2

  // ---- phase 2: bias precompute (dist + truncated RBF + gate) ----
  float4 bgv = *(const float4*)b_gate;
  float4 bdbv = *(const float4*)b_db;
  for (int p = tid; p < KNBR * SUBK; p += 512) {
    int kl = p / SUBK, s = p - kl * SUBK;
    int j = sub_idx[(size_t)(e0 + kl) * SUBK + s];
    sub_lds[p] = (ushortT)j;
    float dx = trs[kl * 3 + 0] - trs[j * 3 + 0] + EPSC;
    float dy = trs[kl * 3 + 1] - trs[j * 3 + 1] + EPSC;
    float dz = trs[kl * 3 + 2] - trs[j * 3 + 2] + EPSC;
    float dist = sqrtf(dx * dx + dy * dy + dz * dz);
    int r0 = (int)(dist * INV_MU_STEP + 0.5f);
    int rlo = max(r0 - 4, 0), rhi = min(r0 + 4, 63);
    float a0 = 0.f, a1 = 0.f, a2 = 0.f, a3 = 0.f;
    for (int r = rlo; r <= rhi; ++r) {
      float t = (dist - r * MU_STEP) * INV_SIGMA;
      float e = __expf(-t * t);
      float4 wv = ((const float4*)W_db)[r];
      a0 += e * wv.x; a1 += e * wv.y; a2 += e * wv.z; a3 += e * wv.w;
    }
    float g1 = gg[kl * 8 + 0] + gg[j * 8 + 4 + 0] + bgv.x;
    float g2 = gg[kl * 8 + 1] + gg[j * 8 + 4 + 1] + bgv.y;
    float g3 = gg[kl * 8 + 2] + gg[j * 8 + 4 + 2] + bgv.z;
    float g4 = gg[kl * 8 + 3] + gg[j * 8 + 4 + 3] + bgv.w;
    biasb[p * 4 + 0] = f2h((a0 + bdbv.x) / (1.0f + __expf(-g1)));
    biasb[p * 4 + 1] = f2h((a1 + bdbv.y) / (1.0f + __expf(-g2)));
    biasb[p * 4 + 2] = f2h((a2 + bdbv.z) / (1.0f + __expf(-g3)));
    biasb[p * 4 + 3] = f2h((a3 + bdbv.w) / (1.0f + __expf(-g4)));
  }
  __syncthreads();  // B: kvb + updq(q) + biasb + sub_lds visible

  // ---- phase 3: attention. lane = (row=tid>>3, h=(tid>>1)&3, dh=tid&1) ----
  int row3 = tid >> 3, h = (tid >> 1) & 3, dh = tid & 1;
  int row3c = min(row3, KNBR - 1);
  int hd = h * 2 + dh;
  const char* kvbase = (const char*)kvb;
  float qh[16];
  {
    const ushortT* qp = updq + row3 * 136 + h * 32 + dh * 16;
    uint4 u0 = *(const uint4*)qp;
    uint4 u1 = *(const uint4*)(qp + 8);
    qh[0] = bflo(u0.x); qh[1] = bfhi(u0.x); qh[2] = bflo(u0.y); qh[3] = bfhi(u0.y);
    qh[4] = bflo(u0.z); qh[5] = bfhi(u0.z); qh[6] = bflo(u0.w); qh[7] = bfhi(u0.w);
    qh[8] = bflo(u1.x); qh[9] = bfhi(u1.x); qh[10] = bflo(u1.y); qh[11] = bfhi(u1.y);
    qh[12] = bflo(u1.z); qh[13] = bfhi(u1.z); qh[14] = bflo(u1.w); qh[15] = bfhi(u1.w);
  }
  float logit[SUBK];
#pragma unroll
  for (int s = 0; s < SUBK; ++s) {
    int j = sub_lds[row3c * SUBK + s];
    int sw = (j & 7) << 4;
    float dot = 0.f;
#pragma unroll
    for (int c = 0; c < 2; ++c) {
      uint4 u = *(const uint4*)(kvbase + j * 512 + ((c * 128 + hd * 16) ^ sw));
      dot += qh[c * 8 + 0] * bflo(u.x) + qh[c * 8 + 1] * bfhi(u.x) +
             qh[c * 8 + 2] * bflo(u.y) + qh[c * 8 + 3] * bfhi(u.y) +
             qh[c * 8 + 4] * bflo(u.z) + qh[c * 8 + 5] * bfhi(u.z) +
             qh[c * 8 + 6] * bflo(u.w) + qh[c * 8 + 7] * bfhi(u.w);
    }
    dot += __shfl_xor(dot, 1);
    logit[s] = dot + h2f(biasb[(row3c * SUBK + s) * 4 + h]);
  }
  float m = logit[0];
#pragma unroll
  for (int s = 1; s < SUBK; ++s) m = fmaxf(m, logit[s]);
  float den = 0.f;
#pragma unroll
  for (int s = 0; s < SUBK; ++s) {
    logit[s] = __expf(logit[s] - m);
    den += logit[s];
  }
  float inv = 1.0f / den;
  float vacc[16];
#pragma unroll
  for (int i = 0; i < 16; ++i) vacc[i] = 0.f;
#pragma unroll
  for (int s = 0; s < SUBK; ++s) {
    int j = sub_lds[row3c * SUBK + s];
    int sw = (j & 7) << 4;
    float wgt = logit[s];
#pragma unroll
    for (int c = 0; c < 2; ++c) {
      uint4 u = *(const uint4*)(kvbase + j * 512 + 256 + ((c * 128 + hd * 16) ^ sw));
      vacc[c * 8 + 0] += wgt * bflo(u.x); vacc[c * 8 + 1] += wgt * bfhi(u.x);
      vacc[c * 8 + 2] += wgt * bflo(u.y); vacc[c * 8 + 3] += wgt * bfhi(u.y);
      vacc[c * 8 + 4] += wgt * bflo(u.z); vacc[c * 8 + 5] += wgt * bfhi(u.z);
      vacc[c * 8 + 6] += wgt * bflo(u.w); vacc[c * 8 + 7] += wgt * bfhi(u.w);
    }
  }
#pragma unroll
  for (int c = 0; c < 2; ++c) {
    uint4 o;
    o.x = pack2bf(vacc[c * 8 + 0] * inv, vacc[c * 8 + 1] * inv);
    o.y = pack2bf(vacc[c * 8 + 2] * inv, vacc[c * 8 + 3] * inv);
    o.z = pack2bf(vacc[c * 8 + 4] * inv, vacc[c * 8 + 5] * inv);
    o.w = pack2bf(vacc[c * 8 + 6] * inv, vacc[c * 8 + 7] * inv);
    *(uint4*)(updq + row3 * 136 + h * 32 + dh * 16 + c * 8) = o;
  }
  __syncthreads();  // C: upd visible

  // ---- phase 4: out projection, 4 col-tiles per group ----
  bf16x8 af2[4];
#pragma unroll
  for (int t = 0; t < 4; ++t)
    af2[t] = *(const bf16x8*)(updq + rowA * 136 + t * 32 + lc * 8);
  int T4base = (tid >> 8) * 4;
#pragma unroll
  for (int Ti = 0; Ti < 4; ++Ti) {
    int T = T4base + Ti;
    f32x4 acc = {0.f, 0.f, 0.f, 0.f};
#pragma unroll
    for (int t = 0; t < 4; ++t) {
      bf16x8 bfrag = *(const bf16x8*)(Wp2 + ((T * 4 + t) * 64 + l) * 8);
      acc = __builtin_amdgcn_mfma_f32_16x16x32_bf16(bfrag, af2[t], acc, 0, 0, 0);
    }
    if (rowA < KNBR) {
      int col0 = T * 16 + lc * 4;
      float4 bi = *(const float4*)(bout + col0);
      float4 o;
      o.x = acc[0] + bi.x; o.y = acc[1] + bi.y;
      o.z = acc[2] + bi.z; o.w = acc[3] + bi.w;
      *(float4*)(outp + (size_t)(e0 + rowA) * 128 + col0) = o;
    }
  }
}

extern "C" void kernel_launch(void* const* d_in, const int* in_sizes, int n_in, void* d_out,
                              int out_size, void* d_ws, size_t ws_size, hipStream_t stream) {
  const float* nf  = (const float*)d_in[0];
  const float* nt  = (const float*)d_in[1];
  const float* ef  = (const float*)d_in[2];
  const int*   ei  = (const int*)d_in[3];
  const int*   si  = (const int*)d_in[4];
  const float* Wg  = (const float*)d_in[5];
  const float* bg  = (const float*)d_in[6];
  const float* Wdb = (const float*)d_in[7];
  const float* bdb = (const float*)d_in[8];
  const float* Wqk = (const float*)d_in[9];
  const float* bqk = (const float*)d_in[10];
  const float* Wv  = (const float*)d_in[11];
  const float* bv  = (const float*)d_in[12];
  const float* Wout = (const float*)d_in[13];
  const float* bout = (const float*)d_in[14];
  float* out = (float*)d_out;  // f32 output

  float* g      = (float*)d_ws;                 // 3072 f32
  float* bc     = g + 3072;                     // 384 f32
  ushortT* Wp1  = (ushortT*)(bc + 384);         // 49152 bf16
  ushortT* Wp2  = Wp1 + 49152;                  // 16384 bf16

  prep_kernel<<<dim3(352), dim3(256), 0, stream>>>(nf, Wg, g, Wqk, bqk, Wv, bv, Wout,
                                                   Wp1, Wp2, bc);
  fused_kernel<<<dim3(N_NODES), dim3(512), 0, stream>>>(ef, Wp1, Wp2, bc, bout, g, nt, ei, si,
                                                        Wdb, bdb, bg, out);
}

// Round 11
// 40.691 us; speedup vs baseline: 2.9107x; 2.9107x over previous
//
#include <hip/hip_runtime.h>
#include <hip/hip_bf16.h>

typedef unsigned short ushortT;
typedef __attribute__((ext_vector_type(8))) short bf16x8;
typedef __attribute__((ext_vector_type(4))) float f32x4;

#define N_NODES 384
#define KNBR 60
#define SUBK 20
#define NEDGE (N_NODES * KNBR)
#define EPSC 1e-8f
#define INV_SQRT_CZ 0.08838834764831845f   // 1/sqrt(128)
#define MU_STEP (20.0f / 63.0f)            // linspace(0,20,64) step
#define INV_MU_STEP (63.0f / 20.0f)
#define INV_SIGMA 3.2f                     // 1/(20/64)

__device__ __forceinline__ float bflo(unsigned int u) { return __uint_as_float(u << 16); }
__device__ __forceinline__ float bfhi(unsigned int u) { return __uint_as_float(u & 0xffff0000u); }
__device__ __forceinline__ ushortT f2bu(float v) {  // f32 -> bf16 bits, RNE
  union { float f; unsigned int u; } c;
  c.f = v;
  return (ushortT)((c.u + 0x7fffu + ((c.u >> 16) & 1u)) >> 16);
}
__device__ __forceinline__ unsigned int pack2bf(float x, float y) {
  return (unsigned int)f2bu(x) | ((unsigned int)f2bu(y) << 16);
}
__device__ __forceinline__ ushortT f2h(float x) {
  _Float16 h = (_Float16)x;
  return __builtin_bit_cast(ushortT, h);
}
__device__ __forceinline__ float h2f(ushortT u) {
  return (float)__builtin_bit_cast(_Float16, u);
}

// Fused prep: blocks 0..95 = gate projection (4 nodes/block, 64 lanes each);
// blocks 96..351 = weight packing into MFMA fragment order + bias concat.
__global__ __launch_bounds__(256) void prep_kernel(
    const float* __restrict__ nf, const float* __restrict__ Wg, float* __restrict__ g,
    const float* __restrict__ Wqk, const float* __restrict__ bqk,
    const float* __restrict__ Wv, const float* __restrict__ bv,
    const float* __restrict__ Wout,
    ushortT* __restrict__ Wp1, ushortT* __restrict__ Wp2, float* __restrict__ bc) {
  int b = blockIdx.x, tid = threadIdx.x;
  if (b < 96) {
    int n = b * 4 + (tid >> 6), t = tid & 63;
    float a = nf[n * 128 + t];
    float bb = nf[n * 128 + 64 + t];
    float acc[8];
#pragma unroll
    for (int h = 0; h < 4; ++h) {
      acc[h]     = a * Wg[t * 4 + h]         + bb * Wg[(t + 64) * 4 + h];
      acc[4 + h] = a * Wg[(128 + t) * 4 + h] + bb * Wg[(192 + t) * 4 + h];
    }
#pragma unroll
    for (int i = 0; i < 8; ++i)
#pragma unroll
      for (int off = 32; off >= 1; off >>= 1) acc[i] += __shfl_xor(acc[i], off, 64);
    if (t == 0) {
#pragma unroll
      for (int i = 0; i < 8; ++i) g[n * 8 + i] = acc[i];
    }
  } else {
    int i = (b - 96) * 256 + tid;  // 65536 total
    if (i < 49152) {
      int j = i & 7, l = (i >> 3) & 63, t = (i >> 9) & 3;
      int nt = (i >> 11) % 12, ny = (i >> 11) / 12;
      int nn = ny * 192 + nt * 16 + (l & 15);
      int k = t * 32 + (l >> 4) * 8 + j;
      float v = (nn < 256) ? Wqk[k * 256 + nn] : Wv[k * 128 + (nn - 256)];
      Wp1[i] = f2bu(v);
    } else {
      int i2 = i - 49152;  // 16384
      int j = i2 & 7, l = (i2 >> 3) & 63, t = (i2 >> 9) & 3, nt = (i2 >> 11);
      int nn = nt * 16 + (l & 15);
      int k = t * 32 + (l >> 4) * 8 + j;
      Wp2[i2] = f2bu(Wout[k * 128 + nn]);
    }
    if (i < 384) bc[i] = (i < 256) ? bqk[i] : bv[i - 256];
  }
}

// One block per node, 512 threads (8 waves, two 4-wave groups). Weights read
// direct from global (once per block -> L2-resident). kvb is c-major conflict-free:
// dim d = hd*16 + c*8 + e at byte c*128 + (hd*16 ^ (row&7)<<4) + 2e. Phase 3 is a
// single-pass online softmax (no max-sub; logits bounded) -> no per-s arrays.
__global__ __launch_bounds__(512, 4) void fused_kernel(
    const float* __restrict__ ef, const ushortT* __restrict__ Wp1,
    const ushortT* __restrict__ Wp2, const float* __restrict__ bc,
    const float* __restrict__ bout, const float* __restrict__ g,
    const float* __restrict__ node_trans, const int* __restrict__ edge_index,
    const int* __restrict__ sub_idx, const float* __restrict__ W_db,
    const float* __restrict__ b_db, const float* __restrict__ b_gate,
    float* __restrict__ outp) {
  __shared__ __align__(16) ushortT kvb[KNBR * 256];     // 30720 B
  __shared__ __align__(16) ushortT updq[64 * 136];      // 17408 B (q then upd)
  __shared__ __align__(16) ushortT biasb[KNBR * SUBK * 4];  // 9600 B, f16
  __shared__ ushortT sub_lds[KNBR * SUBK];              // 2400 B
  __shared__ float trs[KNBR * 3];                       // 720 B
  __shared__ float gg[KNBR * 8];                        // 1920 B

  int n = blockIdx.x, tid = threadIdx.x;
  int e0 = n * KNBR;
  int w = tid >> 6, l = tid & 63;
  int lr = l & 15, lc = l >> 4;
  int rowA = (w & 3) * 16 + lr;          // 0..63 (rows 60..63 pad)
  int rowAc = min(rowA, KNBR - 1);

  // ---- phase 0: stage trs/gg + load A fragments ----
  if (tid < KNBR) {
    int dst = edge_index[e0 + tid];
#pragma unroll
    for (int c = 0; c < 3; ++c) trs[tid * 3 + c] = node_trans[dst * 3 + c];
#pragma unroll
    for (int i = 0; i < 8; ++i) gg[tid * 8 + i] = g[dst * 8 + i];
  }
  bf16x8 afrag[4];
#pragma unroll
  for (int t = 0; t < 4; ++t) {
    const float* ap = ef + (size_t)(e0 + rowAc) * 128 + t * 32 + lc * 8;
    float4 lo = *(const float4*)ap;
    float4 hi = *(const float4*)(ap + 4);
    bf16x8 a;
    a[0] = (short)f2bu(lo.x); a[1] = (short)f2bu(lo.y);
    a[2] = (short)f2bu(lo.z); a[3] = (short)f2bu(lo.w);
    a[4] = (short)f2bu(hi.x); a[5] = (short)f2bu(hi.y);
    a[6] = (short)f2bu(hi.z); a[7] = (short)f2bu(hi.w);
    afrag[t] = a;
  }

  // ---- phase 1: qkv projection, 12 col-tiles per group, no barriers ----
  int Tbase = (tid >> 8) * 12;
#pragma unroll
  for (int Ti = 0; Ti < 12; ++Ti) {
    int T = Tbase + Ti;
    f32x4 acc = {0.f, 0.f, 0.f, 0.f};
#pragma unroll
    for (int t = 0; t < 4; ++t) {
      bf16x8 bfrag = *(const bf16x8*)(Wp1 + ((T * 4 + t) * 64 + l) * 8);
      acc = __builtin_amdgcn_mfma_f32_16x16x32_bf16(bfrag, afrag[t], acc, 0, 0, 0);
    }
    int col0 = T * 16 + lc * 4;
    float4 bi = *(const float4*)(bc + col0);
    float o0 = acc[0] + bi.x, o1 = acc[1] + bi.y;
    float o2 = acc[2] + bi.z, o3 = acc[3] + bi.w;
    if (T < 8) {  // q: scale, straight to updq (bf16)
      uint2 o;
      o.x = pack2bf(o0 * INV_SQRT_CZ, o1 * INV_SQRT_CZ);
      o.y = pack2bf(o2 * INV_SQRT_CZ, o3 * INV_SQRT_CZ);
      *(uint2*)(updq + rowA * 136 + col0) = o;
    } else if (rowA < KNBR) {  // k,v -> kvb (c-major, swizzled)
      uint2 o;
      o.x = pack2bf(o0, o1);
      o.y = pack2bf(o2, o3);
      int colk = col0 - 128;                  // 0..255
      int base_b = (colk & 128) << 1;         // 0 (K) or 256 (V)
      int d = colk & 127;
      int inner = ((d >> 3) & 1) * 128 + (((d >> 4) * 16) ^ ((rowA & 7) << 4)) + (d & 7) * 2;
      *(uint2*)((char*)kvb + rowA * 512 + base_b + inner) = o;
    }
  }
  __syncthreads();  // A: trs/gg visible for phase 2

  // ---- phase 2: bias precompute (dist + truncated RBF + gate) ----
  float4 bgv = *(const float4*)b_gate;
  float4 bdbv = *(const float4*)b_db;
  for (int p = tid; p < KNBR * SUBK; p += 512) {
    int kl = p / SUBK, s = p - kl * SUBK;
    int j = sub_idx[(size_t)(e0 + kl) * SUBK + s];
    sub_lds[p] = (ushortT)j;
    float dx = trs[kl * 3 + 0] - trs[j * 3 + 0] + EPSC;
    float dy = trs[kl * 3 + 1] - trs[j * 3 + 1] + EPSC;
    float dz = trs[kl * 3 + 2] - trs[j * 3 + 2] + EPSC;
    float dist = sqrtf(dx * dx + dy * dy + dz * dz);
    int r0 = (int)(dist * INV_MU_STEP + 0.5f);
    int rlo = max(r0 - 4, 0), rhi = min(r0 + 4, 63);
    float a0 = 0.f, a1 = 0.f, a2 = 0.f, a3 = 0.f;
    for (int r = rlo; r <= rhi; ++r) {
      float t = (dist - r * MU_STEP) * INV_SIGMA;
      float e = __expf(-t * t);
      float4 wv = ((const float4*)W_db)[r];
      a0 += e * wv.x; a1 += e * wv.y; a2 += e * wv.z; a3 += e * wv.w;
    }
    float g1 = gg[kl * 8 + 0] + gg[j * 8 + 4 + 0] + bgv.x;
    float g2 = gg[kl * 8 + 1] + gg[j * 8 + 4 + 1] + bgv.y;
    float g3 = gg[kl * 8 + 2] + gg[j * 8 + 4 + 2] + bgv.z;
    float g4 = gg[kl * 8 + 3] + gg[j * 8 + 4 + 3] + bgv.w;
    biasb[p * 4 + 0] = f2h((a0 + bdbv.x) / (1.0f + __expf(-g1)));
    biasb[p * 4 + 1] = f2h((a1 + bdbv.y) / (1.0f + __expf(-g2)));
    biasb[p * 4 + 2] = f2h((a2 + bdbv.z) / (1.0f + __expf(-g3)));
    biasb[p * 4 + 3] = f2h((a3 + bdbv.w) / (1.0f + __expf(-g4)));
  }
  __syncthreads();  // B: kvb + updq(q) + biasb + sub_lds visible

  // ---- phase 3: attention, single pass (online, no max-sub; logits bounded) ----
  int row3 = tid >> 3, h = (tid >> 1) & 3, dh = tid & 1;
  int row3c = min(row3, KNBR - 1);
  int hdo = (h * 2 + dh) * 16;           // byte offset of this lane's 16B within a 128B half
  const char* kvbase = (const char*)kvb;
  float q0, q1, q2, q3, q4, q5, q6, q7, q8, q9, q10, q11, q12, q13, q14, q15;
  {
    const ushortT* qp = updq + row3 * 136 + h * 32 + dh * 16;
    uint4 u0 = *(const uint4*)qp;
    uint4 u1 = *(const uint4*)(qp + 8);
    q0 = bflo(u0.x); q1 = bfhi(u0.x); q2 = bflo(u0.y); q3 = bfhi(u0.y);
    q4 = bflo(u0.z); q5 = bfhi(u0.z); q6 = bflo(u0.w); q7 = bfhi(u0.w);
    q8 = bflo(u1.x); q9 = bfhi(u1.x); q10 = bflo(u1.y); q11 = bfhi(u1.y);
    q12 = bflo(u1.z); q13 = bfhi(u1.z); q14 = bflo(u1.w); q15 = bfhi(u1.w);
  }
  float den = 0.f;
  float v0 = 0.f, v1 = 0.f, v2 = 0.f, v3 = 0.f, v4 = 0.f, v5 = 0.f, v6 = 0.f, v7 = 0.f;
  float v8 = 0.f, v9 = 0.f, v10 = 0.f, v11 = 0.f, v12 = 0.f, v13 = 0.f, v14 = 0.f, v15 = 0.f;
#pragma unroll 4
  for (int s = 0; s < SUBK; ++s) {
    int j = sub_lds[row3c * SUBK + s];
    int off = hdo ^ ((j & 7) << 4);
    const char* kr = kvbase + j * 512;
    uint4 k0 = *(const uint4*)(kr + off);
    uint4 k1 = *(const uint4*)(kr + 128 + off);
    float dot = q0 * bflo(k0.x) + q1 * bfhi(k0.x) + q2 * bflo(k0.y) + q3 * bfhi(k0.y) +
                q4 * bflo(k0.z) + q5 * bfhi(k0.z) + q6 * bflo(k0.w) + q7 * bfhi(k0.w) +
                q8 * bflo(k1.x) + q9 * bfhi(k1.x) + q10 * bflo(k1.y) + q11 * bfhi(k1.y) +
                q12 * bflo(k1.z) + q13 * bfhi(k1.z) + q14 * bflo(k1.w) + q15 * bfhi(k1.w);
    dot += __shfl_xor(dot, 1);
    float p = __expf(dot + h2f(biasb[(row3c * SUBK + s) * 4 + h]));
    den += p;
    uint4 w0 = *(const uint4*)(kr + 256 + off);
    uint4 w1 = *(const uint4*)(kr + 384 + off);
    v0 += p * bflo(w0.x); v1 += p * bfhi(w0.x); v2 += p * bflo(w0.y); v3 += p * bfhi(w0.y);
    v4 += p * bflo(w0.z); v5 += p * bfhi(w0.z); v6 += p * bflo(w0.w); v7 += p * bfhi(w0.w);
    v8 += p * bflo(w1.x); v9 += p * bfhi(w1.x); v10 += p * bflo(w1.y); v11 += p * bfhi(w1.y);
    v12 += p * bflo(w1.z); v13 += p * bfhi(w1.z); v14 += p * bflo(w1.w); v15 += p * bfhi(w1.w);
  }
  float inv = 1.0f / den;
  {
    uint4 o;
    o.x = pack2bf(v0 * inv, v1 * inv);
    o.y = pack2bf(v2 * inv, v3 * inv);
    o.z = pack2bf(v4 * inv, v5 * inv);
    o.w = pack2bf(v6 * inv, v7 * inv);
    *(uint4*)(updq + row3 * 136 + h * 32 + dh * 16) = o;
    uint4 o2;
    o2.x = pack2bf(v8 * inv, v9 * inv);
    o2.y = pack2bf(v10 * inv, v11 * inv);
    o2.z = pack2bf(v12 * inv, v13 * inv);
    o2.w = pack2bf(v14 * inv, v15 * inv);
    *(uint4*)(updq + row3 * 136 + h * 32 + dh * 16 + 8) = o2;
  }
  __syncthreads();  // C: upd visible

  // ---- phase 4: out projection, 4 col-tiles per group ----
  bf16x8 af2[4];
#pragma unroll
  for (int t = 0; t < 4; ++t)
    af2[t] = *(const bf16x8*)(updq + rowA * 136 + t * 32 + lc * 8);
  int T4base = (tid >> 8) * 4;
#pragma unroll
  for (int Ti = 0; Ti < 4; ++Ti) {
    int T = T4base + Ti;
    f32x4 acc = {0.f, 0.f, 0.f, 0.f};
#pragma unroll
    for (int t = 0; t < 4; ++t) {
      bf16x8 bfrag = *(const bf16x8*)(Wp2 + ((T * 4 + t) * 64 + l) * 8);
      acc = __builtin_amdgcn_mfma_f32_16x16x32_bf16(bfrag, af2[t], acc, 0, 0, 0);
    }
    if (rowA < KNBR) {
      int col0 = T * 16 + lc * 4;
      float4 bi = *(const float4*)(bout + col0);
      float4 o;
      o.x = acc[0] + bi.x; o.y = acc[1] + bi.y;
      o.z = acc[2] + bi.z; o.w = acc[3] + bi.w;
      *(float4*)(outp + (size_t)(e0 + rowA) * 128 + col0) = o;
    }
  }
}

extern "C" void kernel_launch(void* const* d_in, const int* in_sizes, int n_in, void* d_out,
                              int out_size, void* d_ws, size_t ws_size, hipStream_t stream) {
  const float* nf  = (const float*)d_in[0];
  const float* nt  = (const float*)d_in[1];
  const float* ef  = (const float*)d_in[2];
  const int*   ei  = (const int*)d_in[3];
  const int*   si  = (const int*)d_in[4];
  const float* Wg  = (const float*)d_in[5];
  const float* bg  = (const float*)d_in[6];
  const float* Wdb = (const float*)d_in[7];
  const float* bdb = (const float*)d_in[8];
  const float* Wqk = (const float*)d_in[9];
  const float* bqk = (const float*)d_in[10];
  const float* Wv  = (const float*)d_in[11];
  const float* bv  = (const float*)d_in[12];
  const float* Wout = (const float*)d_in[13];
  const float* bout = (const float*)d_in[14];
  float* out = (float*)d_out;  // f32 output

  float* g      = (float*)d_ws;                 // 3072 f32
  float* bc     = g + 3072;                     // 384 f32
  ushortT* Wp1  = (ushortT*)(bc + 384);         // 49152 bf16
  ushortT* Wp2  = Wp1 + 49152;                  // 16384 bf16

  prep_kernel<<<dim3(352), dim3(256), 0, stream>>>(nf, Wg, g, Wqk, bqk, Wv, bv, Wout,
                                                   Wp1, Wp2, bc);
  fused_kernel<<<dim3(N_NODES), dim3(512), 0, stream>>>(ef, Wp1, Wp2, bc, bout, g, nt, ei, si,
                                                        Wdb, bdb, bg, out);
}